// Round 13
// baseline (208.059 us; speedup 1.0000x reference)
//
#include <hip/hip_runtime.h>
#include <hip/hip_bf16.h>

// MoE top-1, single fused persistent kernel (512 blocks x 256 thr).
// N=8192, D=256, H=64, E=32, fp32 (no fp32 MFMA on CDNA4 -> VALU).
// Round-12 structure with the occupancy fix: 16-token router tiles,
// LDS union 51.2 KB -> 3 blocks/CU (12 waves/CU); 512 blocks ~ 543 tiles
// -> ~1 ffn pass per block. Barrier deadlock-safe to 2 blocks/CU (=512).
//
// ws ints: hist[512][32] @0 | eidx[8192] @16384 | arrive[512] @24576

constexpr int D = 256;
constexpr int H = 64;
constexpr int E = 32;
constexpr int T_TILE = 16;
constexpr int NBLK = 512;
constexpr int HIST = 0;
constexpr int EIDX = 16384;
constexpr int ARR  = 24576;
constexpr int MAGIC = 0x51C0FFEE;   // != 0xAAAAAAAA poison

__device__ __forceinline__ float quad_reduce(float v) {
    // sum across the 4 lanes of each quad via DPP quad_perm (VALU-only)
    int i1 = __builtin_bit_cast(int, v);
    v += __builtin_bit_cast(float,
        __builtin_amdgcn_mov_dpp(i1, 0xB1, 0xF, 0xF, true));   // [1,0,3,2]
    int i2 = __builtin_bit_cast(int, v);
    v += __builtin_bit_cast(float,
        __builtin_amdgcn_mov_dpp(i2, 0x4E, 0xF, 0xF, true));   // [2,3,0,1]
    return v;
}

union SU {
    struct {                            // router phase: 51.2 KB
        float4 rwt[64][33];             // [k4][e], padded (33792 B)
        float4 xs[16][64];              // broadcast reads: no pad needed
        float  logitS[16][E + 1];
        int    lcnt[E];
    } r;
    struct {                            // ffn phase: 22.2 KB
        float part[4][T_TILE][H];
        float hsl[T_TILE][H];
        int   scan[256];
        int   rowsl[T_TILE];
        int   cfull[8][E];
        int   cs[E];
    } f;
};

__global__ __launch_bounds__(256) void fused_moe(
    const float* __restrict__ x,  const float* __restrict__ rw,
    const float* __restrict__ rb, const float* __restrict__ W1,
    const float* __restrict__ b1, const float* __restrict__ W2,
    const float* __restrict__ b2, int* __restrict__ wsp,
    float* __restrict__ out)
{
    __shared__ SU su;
    __shared__ int ntile_s;

    const int t = threadIdx.x;
    const int g = blockIdx.x;
    const int n0 = g * 16;

    // ================= phase 1: router (verbatim chains, 16 tokens) ======
    {
        if (t < E) su.r.lcnt[t] = 0;
        const float4* x4 = (const float4*)x;
        const float4* rw4 = (const float4*)rw;
        for (int i = t; i < 32 * 64; i += 256) {     // rw: 2048 float4
            int r = i >> 6, qq = i & 63;
            su.r.rwt[qq][r] = rw4[i];
        }
        for (int i = t; i < 16 * 64; i += 256) {     // x tile: 1024 float4
            int r = i >> 6, qq = i & 63;
            su.r.xs[r][qq] = x4[(size_t)(n0 + r) * 64 + qq];
        }
        __syncthreads();

        {
            const int e = t & 31, gg = t >> 5;       // 2 tokens per thread
            float s[2];
#pragma unroll
            for (int j = 0; j < 2; ++j) s[j] = rb[e];
#pragma unroll
            for (int p = 0; p < 8; ++p) {
                float sp[2] = {0.f, 0.f};
#pragma unroll
                for (int k4 = 0; k4 < 8; ++k4) {
                    float4 wv = su.r.rwt[p * 8 + k4][e];
#pragma unroll
                    for (int j = 0; j < 2; ++j) {
                        float4 xv = su.r.xs[gg * 2 + j][p * 8 + k4];
                        sp[j] = fmaf(xv.x, wv.x, sp[j]);
                        sp[j] = fmaf(xv.y, wv.y, sp[j]);
                        sp[j] = fmaf(xv.z, wv.z, sp[j]);
                        sp[j] = fmaf(xv.w, wv.w, sp[j]);
                    }
                }
#pragma unroll
                for (int j = 0; j < 2; ++j) s[j] += sp[j];
            }
#pragma unroll
            for (int j = 0; j < 2; ++j) su.r.logitS[gg * 2 + j][e] = s[j];
        }
        __syncthreads();

        if (t < 16) {
            float best = su.r.logitS[t][0];
            int bi = 0;
#pragma unroll
            for (int i = 1; i < E; ++i) {
                float v = su.r.logitS[t][i];
                if (v > best) { best = v; bi = i; }  // strict >: first occur.
            }
            wsp[EIDX + n0 + t] = bi;
            atomicAdd(&su.r.lcnt[bi], 1);            // LDS atomic only
        }
        __syncthreads();
        if (t < E) wsp[HIST + g * E + t] = su.r.lcnt[t];
    }

    // ================= device-scope flag barrier ========================
    __syncthreads();
    __threadfence();
    if (t == 0)
        __hip_atomic_store(&wsp[ARR + g], MAGIC,
                           __ATOMIC_RELEASE, __HIP_MEMORY_SCOPE_AGENT);
    while (__hip_atomic_load(&wsp[ARR + t],
                             __ATOMIC_ACQUIRE, __HIP_MEMORY_SCOPE_AGENT)
           != MAGIC)
        __builtin_amdgcn_s_sleep(2);
    while (__hip_atomic_load(&wsp[ARR + t + 256],
                             __ATOMIC_ACQUIRE, __HIP_MEMORY_SCOPE_AGENT)
           != MAGIC)
        __builtin_amdgcn_s_sleep(2);
    __syncthreads();

    // ================= counts + tile count ==============================
    {
        const int c = t >> 5, e2 = t & 31;           // 8 chunks x 64 rows
        int full = 0;
        for (int i = 0; i < 64; ++i)
            full += wsp[HIST + (c * 64 + i) * E + e2];   // coalesced, L2-hot
        su.f.cfull[c][e2] = full;
    }
    __syncthreads();
    if (t < E) {
        int tot = 0;
#pragma unroll
        for (int c2 = 0; c2 < 8; ++c2) tot += su.f.cfull[c2][t];
        su.f.cs[t] = tot;
    }
    __syncthreads();
    if (t == 0) {
        int nt = 0;
        for (int e2 = 0; e2 < E; ++e2) nt += (su.f.cs[e2] + 15) >> 4;
        ntile_s = nt;
    }
    __syncthreads();
    const int numTiles = ntile_s;       // in [512, 543]

    const int lane = t & 63;
    const int w = t >> 6;
    const int s = lane & 3;
    const int q = lane >> 2;

    // ================= phase 2: ffn tiles ===============================
    for (int pass = 0; pass < 2; ++pass) {
        const int tile = g + pass * NBLK;
        if (tile >= numTiles) break;    // uniform across block
        __syncthreads();                // protect LDS reuse across passes

        // self-locate (every thread; uniform)
        int e = -1, slot = 0;
        {
            int b = tile;
#pragma unroll 1
            for (int e2 = 0; e2 < E; ++e2) {
                const int nt = (su.f.cs[e2] + 15) >> 4;
                if (e < 0) {
                    if (b < nt) { e = e2; slot = b; }
                    else b -= nt;
                }
            }
        }
        const int lo = slot * 16;
        const int cnt = min(T_TILE, su.f.cs[e] - lo);

        // token collection: rank-scan of eidx (thread t owns [32t,32t+32))
        int mycount = 0;
        {
            const int* ep = wsp + EIDX + 32 * t;
#pragma unroll
            for (int i = 0; i < 32; ++i) mycount += (ep[i] == e);
        }
        su.f.scan[t] = mycount;
        __syncthreads();
        for (int d2 = 1; d2 < 256; d2 <<= 1) {      // Hillis-Steele
            int v = su.f.scan[t];
            int u = (t >= d2) ? su.f.scan[t - d2] : 0;
            __syncthreads();
            su.f.scan[t] = v + u;
            __syncthreads();
        }
        {
            int r = su.f.scan[t] - mycount;         // exclusive base
            const int* ep = wsp + EIDX + 32 * t;
#pragma unroll
            for (int i = 0; i < 32; ++i) {
                if (ep[i] == e) {
                    if (r >= lo && r < lo + T_TILE)
                        su.f.rowsl[r - lo] = 32 * t + i;
                    ++r;
                }
            }
        }
        __syncthreads();

        // -------- ffn core (round-11/12 verbatim) --------
        const float* w1e = W1 + (size_t)e * (D * H);
        float4 w1v[16];
        {
            const float* base = w1e + (size_t)((w * 4 + s) * 16) * H + 4 * q;
#pragma unroll
            for (int k = 0; k < 16; ++k)
                w1v[k] = *(const float4*)(base + k * H);
        }

#define LOADX(buf, row) {                                                  \
        const float* xb_ = x + (size_t)(row) * D + (w * 4 + s) * 16;       \
        buf[0] = *(const float4*)(xb_ + 0);                                \
        buf[1] = *(const float4*)(xb_ + 4);                                \
        buf[2] = *(const float4*)(xb_ + 8);                                \
        buf[3] = *(const float4*)(xb_ + 12); }

#define BODY1(tok, xb) {                                                   \
        float sp0 = 0.f, sp1 = 0.f, sp2 = 0.f, sp3 = 0.f;                  \
        _Pragma("unroll")                                                  \
        for (int k4 = 0; k4 < 4; ++k4) {                                   \
            float4 xv = xb[k4];                                            \
            _Pragma("unroll")                                              \
            for (int m = 0; m < 4; ++m) {                                  \
                const int k = k4 * 4 + m;                                  \
                const float xs_ = (m == 0) ? xv.x : (m == 1) ? xv.y        \
                                 : (m == 2) ? xv.z : xv.w;                 \
                sp0 = fmaf(xs_, w1v[k].x, sp0);                            \
                sp1 = fmaf(xs_, w1v[k].y, sp1);                            \
                sp2 = fmaf(xs_, w1v[k].z, sp2);                            \
                sp3 = fmaf(xs_, w1v[k].w, sp3);                            \
            }                                                              \
        }                                                                  \
        sp0 = quad_reduce(sp0); sp1 = quad_reduce(sp1);                    \
        sp2 = quad_reduce(sp2); sp3 = quad_reduce(sp3);                    \
        float a_ = (s & 1) ? sp1 : sp0;                                    \
        float c_ = (s & 1) ? sp3 : sp2;                                    \
        su.f.part[w][tok][4 * q + s] = (s & 2) ? c_ : a_; }

        {
            float4 xa[4], xb4[4];
            LOADX(xa, su.f.rowsl[0]);
            for (int tok = 0; tok < cnt; tok += 2) {
                if (tok + 1 < cnt) LOADX(xb4, su.f.rowsl[tok + 1]);
                BODY1(tok, xa);
                if (tok + 1 < cnt) {
                    if (tok + 2 < cnt) LOADX(xa, su.f.rowsl[tok + 2]);
                    BODY1(tok + 1, xb4);
                }
            }
        }

        // W2 staging overlaps the barrier + relu phase
        const float* w2e = W2 + (size_t)e * (H * D);
        float4 w2v[16];
        {
            const float* base = w2e + (size_t)(16 * s) * D + 64 * w + 4 * q;
#pragma unroll
            for (int k = 0; k < 16; ++k)
                w2v[k] = *(const float4*)(base + k * D);
        }
        const float b2v = b2[e * D + 64 * w + 4 * q + s];
        __syncthreads();

        // cross-wave reduce + bias + relu -> hsl
        {
            const int h = t & 63;
            const int tq = t >> 6;
            const float b1v = b1[e * H + h];
#pragma unroll
            for (int r2 = 0; r2 < 4; ++r2) {
                const int tok = tq * 4 + r2;
                if (tok < cnt) {
                    float v = su.f.part[0][tok][h] + su.f.part[1][tok][h]
                            + su.f.part[2][tok][h] + su.f.part[3][tok][h] + b1v;
                    su.f.hsl[tok][h] = fmaxf(v, 0.f);
                }
            }
        }
        __syncthreads();

#define LOADH(buf, tok) {                                                  \
        const float* hb_ = &su.f.hsl[tok][s * 16];                         \
        buf[0] = *(const float4*)(hb_ + 0);                                \
        buf[1] = *(const float4*)(hb_ + 4);                                \
        buf[2] = *(const float4*)(hb_ + 8);                                \
        buf[3] = *(const float4*)(hb_ + 12); }

#define BODY2(tok, hb) {                                                   \
        float sp0 = 0.f, sp1 = 0.f, sp2 = 0.f, sp3 = 0.f;                  \
        _Pragma("unroll")                                                  \
        for (int k4 = 0; k4 < 4; ++k4) {                                   \
            float4 hv = hb[k4];                                            \
            _Pragma("unroll")                                              \
            for (int m = 0; m < 4; ++m) {                                  \
                const int k = k4 * 4 + m;                                  \
                const float hs_ = (m == 0) ? hv.x : (m == 1) ? hv.y        \
                                 : (m == 2) ? hv.z : hv.w;                 \
                sp0 = fmaf(hs_, w2v[k].x, sp0);                            \
                sp1 = fmaf(hs_, w2v[k].y, sp1);                            \
                sp2 = fmaf(hs_, w2v[k].z, sp2);                            \
                sp3 = fmaf(hs_, w2v[k].w, sp3);                            \
            }                                                              \
        }                                                                  \
        sp0 = quad_reduce(sp0); sp1 = quad_reduce(sp1);                    \
        sp2 = quad_reduce(sp2); sp3 = quad_reduce(sp3);                    \
        float a_ = (s & 1) ? sp1 : sp0;                                    \
        float c_ = (s & 1) ? sp3 : sp2;                                    \
        const float val_ = ((s & 2) ? c_ : a_) + b2v;                      \
        const int row_ = su.f.rowsl[tok];                                  \
        out[(size_t)row_ * D + 64 * w + 4 * q + s] = fmaxf(val_, 0.f); }

        {
            float4 ha[4], hb4[4];
            LOADH(ha, 0);
            for (int tok = 0; tok < cnt; tok += 2) {
                if (tok + 1 < cnt) LOADH(hb4, tok + 1);
                BODY2(tok, ha);
                if (tok + 1 < cnt) {
                    if (tok + 2 < cnt) LOADH(ha, tok + 2);
                    BODY2(tok + 1, hb4);
                }
            }
        }
#undef LOADX
#undef BODY1
#undef LOADH
#undef BODY2
    }
}

extern "C" void kernel_launch(void* const* d_in, const int* in_sizes, int n_in,
                              void* d_out, int out_size, void* d_ws, size_t ws_size,
                              hipStream_t stream) {
    const float* x  = (const float*)d_in[0];
    const float* rw = (const float*)d_in[1];
    const float* rb = (const float*)d_in[2];
    const float* W1 = (const float*)d_in[3];
    const float* b1 = (const float*)d_in[4];
    const float* W2 = (const float*)d_in[5];
    const float* b2 = (const float*)d_in[6];
    float* out = (float*)d_out;
    int* ws = (int*)d_ws;

    fused_moe<<<NBLK, 256, 0, stream>>>(x, rw, rb, W1, b1, W2, b2, ws, out);
}